// Round 9
// baseline (218.019 us; speedup 1.0000x reference)
//
#include <hip/hip_runtime.h>

// SAGEEncoder: 2-layer GraphSAGE, mean aggregation.
//   h1 = relu(mean_agg(x) @ Wl1 + x @ Wr1 + b1)
//   h2 = relu(mean_agg(h1) @ Wl2 + h1 @ Wr2 + b2)
//   out[pos_idx] = h2 ; rest of [PAD_N,128] zero.
// R9: CSR entries stored as uint16 (src ids < 50000 < 65536) -> halves the
//     partial-line RMW traffic of the scatter fill (R8's bottleneck).
//     4 dispatches: init+swizzle | cvt+fill | layer1 | layer2.

#define NF 128
#define CAP 64           // CSR slots per node (Poisson(12): P(deg>64) ~ 1e-26)

typedef _Float16 f16x8 __attribute__((ext_vector_type(8)));
typedef _Float16 f16x4 __attribute__((ext_vector_type(4)));
typedef float f32x4 __attribute__((ext_vector_type(4)));

// ---------------- weight swizzle (device) ----------------
// Wf[frag=(s*8+c)][lane][j] = Wcat[c*32 + (lane>>4)*8 + j][s*16 + (lane&15)],
// Wcat rows 0..127 = Wl, 128..255 = Wr.  t in [0, 4096).
__device__ __forceinline__ void swizzle_w(const float* __restrict__ Wl,
                                          const float* __restrict__ Wr,
                                          _Float16* __restrict__ Wf, int t) {
    int lane = t & 63;
    int frag = t >> 6;
    int s = frag >> 3, c = frag & 7;
    int n = s * 16 + (lane & 15);
    int kbase = c * 32 + (lane >> 4) * 8;
    f16x8 v;
#pragma unroll
    for (int j = 0; j < 8; ++j) {
        int k = kbase + j;
        float f = (k < NF) ? Wl[k * NF + n] : Wr[(k - NF) * NF + n];
        v[j] = (_Float16)f;
    }
    ((f16x8*)Wf)[frag * 64 + lane] = v;
}

// ---------------- K1: zero out-tail + deg | swizzle W1/W2 ----------------
__global__ void init_swz_kernel(float4* __restrict__ tail, int n4tail,
                                int4* __restrict__ deg4, int ndeg4,
                                const float* __restrict__ Wl1, const float* __restrict__ Wr1,
                                _Float16* __restrict__ Wf1,
                                const float* __restrict__ Wl2, const float* __restrict__ Wr2,
                                _Float16* __restrict__ Wf2) {
    int nbt = (n4tail + 255) >> 8;
    int nbd = (ndeg4 + 255) >> 8;
    int b = blockIdx.x;
    if (b < nbt) {
        int i = b * 256 + threadIdx.x;
        if (i < n4tail) tail[i] = make_float4(0.f, 0.f, 0.f, 0.f);
    } else if (b < nbt + nbd) {
        int i = (b - nbt) * 256 + threadIdx.x;
        if (i < ndeg4) deg4[i] = make_int4(0, 0, 0, 0);
    } else if (b < nbt + nbd + 16) {
        swizzle_w(Wl1, Wr1, Wf1, (b - nbt - nbd) * 256 + threadIdx.x);
    } else {
        swizzle_w(Wl2, Wr2, Wf2, (b - nbt - nbd - 16) * 256 + threadIdx.x);
    }
}

// ---------------- K2: cvt x->f16 | self-allocating CSR fill (u16 entries) ----------------
__global__ void cvt_fill_kernel(const float4* __restrict__ x4, f16x4* __restrict__ xh4,
                                int n4x,
                                const int* __restrict__ src, const int* __restrict__ dst,
                                int* __restrict__ deg, unsigned short* __restrict__ csr,
                                int E) {
    int nbc = (n4x + 255) >> 8;
    int b = blockIdx.x;
    if (b < nbc) {
        int i = b * 256 + threadIdx.x;
        if (i < n4x) {
            float4 v = x4[i];
            f16x4 o;
            o[0] = (_Float16)v.x; o[1] = (_Float16)v.y;
            o[2] = (_Float16)v.z; o[3] = (_Float16)v.w;
            xh4[i] = o;
        }
    } else {
        int e = (b - nbc) * 256 + threadIdx.x;
        if (e < E) {
            int s = src[e];
            int d = dst[e];
            int slot = atomicAdd(&deg[d], 1);
            if (slot < CAP) csr[d * CAP + slot] = (unsigned short)s;
        }
    }
}

// ---------------- K3/K4: fused gather + MFMA layer ----------------
// Block = 256 thr (4 waves) = 16 nodes. Phase 1: each (wave,sub) gathers one
// node (4 independent chains/wave); agg tile -> LDS. Phase 2: 16x16 MFMA tile;
// agg A-frags from LDS, self A-frags from global, B-frags in registers.
// C layout: col(feat)=lane&15, row(node)=quad*4+r.
#define LDA 136          // LDS row stride (f16): 2-way max bank aliasing
template <bool LAST>
__global__ __launch_bounds__(256) void sage_layer_fused(
    const unsigned short* __restrict__ csr, const int* __restrict__ deg,
    const _Float16* __restrict__ H,    // input activations [Nn,128] f16
    const _Float16* __restrict__ Wf,   // frag-order [Wl;Wr]
    const float* __restrict__ bias,
    const int* __restrict__ pos,
    _Float16* __restrict__ outh,       // !LAST: h1 f16
    float* __restrict__ outf,          // LAST: padded out f32
    int Nn) {
    __shared__ _Float16 sA[16][LDA];

    const int wave = threadIdx.x >> 6;
    const int lane = threadIdx.x & 63;
    const int sub  = lane >> 4;        // 0..3  (quad in MFMA phase)
    const int li   = lane & 15;        // 0..15 (mrow in MFMA phase)
    const int m0 = blockIdx.x * 16;

    // ---- phase 1: gather-mean, one node per (wave,sub) ----
    {
        int n = m0 + wave * 4 + sub;
        float a[8] = {0.f, 0.f, 0.f, 0.f, 0.f, 0.f, 0.f, 0.f};
        float b[8] = {0.f, 0.f, 0.f, 0.f, 0.f, 0.f, 0.f, 0.f};
        float inv = 1.0f;
        if (n < Nn) {
            int dg = deg[n];
            int rs = n * CAP;
            int re = rs + ((dg < CAP) ? dg : CAP);
            const f16x8* Hp = (const f16x8*)H;
            int k = rs;
            for (; k + 4 <= re; k += 4) {
                f16x8 v0 = Hp[(size_t)csr[k] * 16 + li];
                f16x8 v1 = Hp[(size_t)csr[k + 1] * 16 + li];
                f16x8 v2 = Hp[(size_t)csr[k + 2] * 16 + li];
                f16x8 v3 = Hp[(size_t)csr[k + 3] * 16 + li];
#pragma unroll
                for (int j = 0; j < 8; ++j) {
                    a[j] += (float)v0[j] + (float)v2[j];
                    b[j] += (float)v1[j] + (float)v3[j];
                }
            }
            if (k + 2 <= re) {
                f16x8 v0 = Hp[(size_t)csr[k] * 16 + li];
                f16x8 v1 = Hp[(size_t)csr[k + 1] * 16 + li];
#pragma unroll
                for (int j = 0; j < 8; ++j) { a[j] += (float)v0[j]; b[j] += (float)v1[j]; }
                k += 2;
            }
            if (k < re) {
                f16x8 v0 = Hp[(size_t)csr[k] * 16 + li];
#pragma unroll
                for (int j = 0; j < 8; ++j) a[j] += (float)v0[j];
            }
            inv = 1.0f / fmaxf((float)dg, 1.0f);
        }
        f16x8 r;
#pragma unroll
        for (int j = 0; j < 8; ++j) r[j] = (_Float16)((a[j] + b[j]) * inv);
        *(f16x8*)&sA[wave * 4 + sub][li * 8] = r;
    }

    // B-frags: issued here so the loads drain during the barrier
    f16x8 bfrag[2][8];
    const f16x8* wfp = (const f16x8*)Wf;
#pragma unroll
    for (int s = 0; s < 2; ++s)
#pragma unroll
        for (int c = 0; c < 8; ++c)
            bfrag[s][c] = wfp[((2 * wave + s) * 8 + c) * 64 + lane];

    __syncthreads();

    // ---- phase 2: MFMA, 2 output strips per wave ----
    f32x4 acc[2] = {(f32x4){0.f, 0.f, 0.f, 0.f}, (f32x4){0.f, 0.f, 0.f, 0.f}};

#pragma unroll
    for (int c = 0; c < 4; ++c) {          // agg half (K 0..127)
        f16x8 af = *(const f16x8*)&sA[li][c * 32 + sub * 8];
        acc[0] = __builtin_amdgcn_mfma_f32_16x16x32_f16(af, bfrag[0][c], acc[0], 0, 0, 0);
        acc[1] = __builtin_amdgcn_mfma_f32_16x16x32_f16(af, bfrag[1][c], acc[1], 0, 0, 0);
    }
    {
        int nd = m0 + li; if (nd >= Nn) nd = Nn - 1;
        const _Float16* xrow = H + (size_t)nd * NF;
#pragma unroll
        for (int c = 0; c < 4; ++c) {      // self half (K 128..255)
            f16x8 af = *(const f16x8*)(xrow + c * 32 + sub * 8);
            acc[0] = __builtin_amdgcn_mfma_f32_16x16x32_f16(af, bfrag[0][4 + c], acc[0], 0, 0, 0);
            acc[1] = __builtin_amdgcn_mfma_f32_16x16x32_f16(af, bfrag[1][4 + c], acc[1], 0, 0, 0);
        }
    }

    // ---- epilogue ----
#pragma unroll
    for (int s = 0; s < 2; ++s) {
        int feat = (2 * wave + s) * 16 + li;
        float bv = bias[feat];
#pragma unroll
        for (int r = 0; r < 4; ++r) {
            int node = m0 + sub * 4 + r;
            if (node < Nn) {
                float v = fmaxf(acc[s][r] + bv, 0.f);
                if (LAST) outf[(size_t)pos[node] * NF + feat] = v;
                else      outh[(size_t)node * NF + feat] = (_Float16)v;
            }
        }
    }
}

extern "C" void kernel_launch(void* const* d_in, const int* in_sizes, int n_in,
                              void* d_out, int out_size, void* d_ws, size_t ws_size,
                              hipStream_t stream) {
    const float* x   = (const float*)d_in[0];
    const int*   ei  = (const int*)d_in[1];   // [2,E] int32
    const int*   pos = (const int*)d_in[2];   // [N] int32 (== arange(N))
    const float* Wl1 = (const float*)d_in[4];
    const float* Wr1 = (const float*)d_in[5];
    const float* b1  = (const float*)d_in[6];
    const float* Wl2 = (const float*)d_in[7];
    const float* Wr2 = (const float*)d_in[8];
    const float* b2  = (const float*)d_in[9];
    float* out = (float*)d_out;

    const int Nn = in_sizes[0] / NF;      // 50000
    const int E  = in_sizes[1] / 2;       // 600000
    const int* src = ei;
    const int* dst = ei + E;
    const int pad_rows = out_size / NF;   // 60000

    // workspace: xh | h1h (Nn*NF f16) | Wf1 | Wf2 (32768 f16) |
    //            deg[degN] | csr[Nn*CAP] u16      (~33 MB)
    const int degN = (Nn + 3) & ~3;
    _Float16* xh   = (_Float16*)d_ws;
    _Float16* h1h  = xh + (size_t)Nn * NF;
    _Float16* Wf1  = h1h + (size_t)Nn * NF;
    _Float16* Wf2  = Wf1 + 64 * 64 * 8;
    int* deg       = (int*)(Wf2 + 64 * 64 * 8);
    unsigned short* csr = (unsigned short*)(deg + degN);

    const int ZB = 256;

    // K1: zero out-tail + deg, swizzle weights
    int n4tail = (pad_rows - Nn) * NF / 4;
    int ndeg4  = degN / 4;
    int nbt = (n4tail + ZB - 1) / ZB, nbd = (ndeg4 + ZB - 1) / ZB;
    init_swz_kernel<<<nbt + nbd + 32, ZB, 0, stream>>>(
        (float4*)(out + (size_t)Nn * NF), n4tail, (int4*)deg, ndeg4,
        Wl1, Wr1, Wf1, Wl2, Wr2, Wf2);

    // K2: cvt + self-allocating CSR fill
    int n4x = Nn * NF / 4;
    int nbc = (n4x + ZB - 1) / ZB;
    cvt_fill_kernel<<<nbc + (E + ZB - 1) / ZB, ZB, 0, stream>>>(
        (const float4*)x, (f16x4*)xh, n4x, src, dst, deg, csr, E);

    // K3/K4: fused layers (16 nodes per block)
    const int fblocks = (Nn + 15) / 16;   // 3125
    sage_layer_fused<false><<<fblocks, ZB, 0, stream>>>(
        csr, deg, xh, Wf1, b1, nullptr, h1h, nullptr, Nn);
    sage_layer_fused<true><<<fblocks, ZB, 0, stream>>>(
        csr, deg, h1h, Wf2, b2, pos, nullptr, out, Nn);
}

// Round 10
// 213.628 us; speedup vs baseline: 1.0206x; 1.0206x over previous
//
#include <hip/hip_runtime.h>

// SAGEEncoder: 2-layer GraphSAGE, mean aggregation.
//   h1 = relu(mean_agg(x) @ Wl1 + x @ Wr1 + b1)
//   h2 = relu(mean_agg(h1) @ Wl2 + h1 @ Wr2 + b2)
//   out[pos_idx] = h2 ; rest of [PAD_N,128] zero.
// R10: u32 CSR restored (u16 scatter regressed: sub-dword L2 RMW is slower);
//      nt-stores for the csr scatter; K1+K2 merged into one mega-kernel with
//      fill blocks first (long pole). deg zeroed via hipMemsetAsync.
//      Dispatches: memset | mega | layer1 | layer2.

#define NF 128
#define CAP 64           // CSR slots per node (Poisson(12): P(deg>64) ~ 1e-26)

typedef _Float16 f16x8 __attribute__((ext_vector_type(8)));
typedef _Float16 f16x4 __attribute__((ext_vector_type(4)));
typedef float f32x4 __attribute__((ext_vector_type(4)));

// ---------------- weight swizzle (device) ----------------
// Wf[frag=(s*8+c)][lane][j] = Wcat[c*32 + (lane>>4)*8 + j][s*16 + (lane&15)],
// Wcat rows 0..127 = Wl, 128..255 = Wr.  t in [0, 4096).
__device__ __forceinline__ void swizzle_w(const float* __restrict__ Wl,
                                          const float* __restrict__ Wr,
                                          _Float16* __restrict__ Wf, int t) {
    int lane = t & 63;
    int frag = t >> 6;
    int s = frag >> 3, c = frag & 7;
    int n = s * 16 + (lane & 15);
    int kbase = c * 32 + (lane >> 4) * 8;
    f16x8 v;
#pragma unroll
    for (int j = 0; j < 8; ++j) {
        int k = kbase + j;
        float f = (k < NF) ? Wl[k * NF + n] : Wr[(k - NF) * NF + n];
        v[j] = (_Float16)f;
    }
    ((f16x8*)Wf)[frag * 64 + lane] = v;
}

// ---------------- mega kernel: fill | cvt | out-tail zero | swizzle ----------------
// Block ranges (in launch order -> dispatch order): fill first (long pole:
// 600K atomics + scattered stores, L2 line-op bound), then cvt / zero /
// swizzle backfill the remaining CUs.
__global__ void mega_prep_kernel(const int* __restrict__ src, const int* __restrict__ dst,
                                 int* __restrict__ deg, int* __restrict__ csr, int E,
                                 const float4* __restrict__ x4, f16x4* __restrict__ xh4,
                                 int n4x,
                                 float4* __restrict__ tail, int n4tail,
                                 const float* __restrict__ Wl1, const float* __restrict__ Wr1,
                                 _Float16* __restrict__ Wf1,
                                 const float* __restrict__ Wl2, const float* __restrict__ Wr2,
                                 _Float16* __restrict__ Wf2) {
    int nbe = (E + 255) >> 8;
    int nbc = (n4x + 255) >> 8;
    int nbt = (n4tail + 255) >> 8;
    int b = blockIdx.x;
    if (b < nbe) {
        int e = b * 256 + threadIdx.x;
        if (e < E) {
            int s = src[e];
            int d = dst[e];
            int slot = atomicAdd(&deg[d], 1);
            if (slot < CAP) __builtin_nontemporal_store(s, &csr[d * CAP + slot]);
        }
    } else if (b < nbe + nbc) {
        int i = (b - nbe) * 256 + threadIdx.x;
        if (i < n4x) {
            float4 v = x4[i];
            f16x4 o;
            o[0] = (_Float16)v.x; o[1] = (_Float16)v.y;
            o[2] = (_Float16)v.z; o[3] = (_Float16)v.w;
            xh4[i] = o;
        }
    } else if (b < nbe + nbc + nbt) {
        int i = (b - nbe - nbc) * 256 + threadIdx.x;
        if (i < n4tail) tail[i] = make_float4(0.f, 0.f, 0.f, 0.f);
    } else if (b < nbe + nbc + nbt + 16) {
        swizzle_w(Wl1, Wr1, Wf1, (b - nbe - nbc - nbt) * 256 + threadIdx.x);
    } else {
        swizzle_w(Wl2, Wr2, Wf2, (b - nbe - nbc - nbt - 16) * 256 + threadIdx.x);
    }
}

// ---------------- fused gather + MFMA layer ----------------
// Block = 256 thr (4 waves) = 16 nodes. Phase 1: each (wave,sub) gathers one
// node (4 independent chains/wave); agg tile -> LDS. Phase 2: 16x16 MFMA tile;
// agg A-frags from LDS, self A-frags from global, B-frags in registers.
// C layout: col(feat)=lane&15, row(node)=quad*4+r.
#define LDA 136          // LDS row stride (f16): 2-way max bank aliasing
template <bool LAST>
__global__ __launch_bounds__(256) void sage_layer_fused(
    const int* __restrict__ csr, const int* __restrict__ deg,
    const _Float16* __restrict__ H,    // input activations [Nn,128] f16
    const _Float16* __restrict__ Wf,   // frag-order [Wl;Wr]
    const float* __restrict__ bias,
    const int* __restrict__ pos,
    _Float16* __restrict__ outh,       // !LAST: h1 f16
    float* __restrict__ outf,          // LAST: padded out f32
    int Nn) {
    __shared__ _Float16 sA[16][LDA];

    const int wave = threadIdx.x >> 6;
    const int lane = threadIdx.x & 63;
    const int sub  = lane >> 4;        // 0..3  (quad in MFMA phase)
    const int li   = lane & 15;        // 0..15 (mrow in MFMA phase)
    const int m0 = blockIdx.x * 16;

    // ---- phase 1: gather-mean, one node per (wave,sub) ----
    {
        int n = m0 + wave * 4 + sub;
        float a[8] = {0.f, 0.f, 0.f, 0.f, 0.f, 0.f, 0.f, 0.f};
        float b[8] = {0.f, 0.f, 0.f, 0.f, 0.f, 0.f, 0.f, 0.f};
        float inv = 1.0f;
        if (n < Nn) {
            int dg = deg[n];
            int rs = n * CAP;
            int re = rs + ((dg < CAP) ? dg : CAP);
            const f16x8* Hp = (const f16x8*)H;
            int k = rs;
            for (; k + 4 <= re; k += 4) {
                f16x8 v0 = Hp[(size_t)csr[k] * 16 + li];
                f16x8 v1 = Hp[(size_t)csr[k + 1] * 16 + li];
                f16x8 v2 = Hp[(size_t)csr[k + 2] * 16 + li];
                f16x8 v3 = Hp[(size_t)csr[k + 3] * 16 + li];
#pragma unroll
                for (int j = 0; j < 8; ++j) {
                    a[j] += (float)v0[j] + (float)v2[j];
                    b[j] += (float)v1[j] + (float)v3[j];
                }
            }
            if (k + 2 <= re) {
                f16x8 v0 = Hp[(size_t)csr[k] * 16 + li];
                f16x8 v1 = Hp[(size_t)csr[k + 1] * 16 + li];
#pragma unroll
                for (int j = 0; j < 8; ++j) { a[j] += (float)v0[j]; b[j] += (float)v1[j]; }
                k += 2;
            }
            if (k < re) {
                f16x8 v0 = Hp[(size_t)csr[k] * 16 + li];
#pragma unroll
                for (int j = 0; j < 8; ++j) a[j] += (float)v0[j];
            }
            inv = 1.0f / fmaxf((float)dg, 1.0f);
        }
        f16x8 r;
#pragma unroll
        for (int j = 0; j < 8; ++j) r[j] = (_Float16)((a[j] + b[j]) * inv);
        *(f16x8*)&sA[wave * 4 + sub][li * 8] = r;
    }

    // B-frags: issued here so the loads drain during the barrier
    f16x8 bfrag[2][8];
    const f16x8* wfp = (const f16x8*)Wf;
#pragma unroll
    for (int s = 0; s < 2; ++s)
#pragma unroll
        for (int c = 0; c < 8; ++c)
            bfrag[s][c] = wfp[((2 * wave + s) * 8 + c) * 64 + lane];

    __syncthreads();

    // ---- phase 2: MFMA, 2 output strips per wave ----
    f32x4 acc[2] = {(f32x4){0.f, 0.f, 0.f, 0.f}, (f32x4){0.f, 0.f, 0.f, 0.f}};

#pragma unroll
    for (int c = 0; c < 4; ++c) {          // agg half (K 0..127)
        f16x8 af = *(const f16x8*)&sA[li][c * 32 + sub * 8];
        acc[0] = __builtin_amdgcn_mfma_f32_16x16x32_f16(af, bfrag[0][c], acc[0], 0, 0, 0);
        acc[1] = __builtin_amdgcn_mfma_f32_16x16x32_f16(af, bfrag[1][c], acc[1], 0, 0, 0);
    }
    {
        int nd = m0 + li; if (nd >= Nn) nd = Nn - 1;
        const _Float16* xrow = H + (size_t)nd * NF;
#pragma unroll
        for (int c = 0; c < 4; ++c) {      // self half (K 128..255)
            f16x8 af = *(const f16x8*)(xrow + c * 32 + sub * 8);
            acc[0] = __builtin_amdgcn_mfma_f32_16x16x32_f16(af, bfrag[0][4 + c], acc[0], 0, 0, 0);
            acc[1] = __builtin_amdgcn_mfma_f32_16x16x32_f16(af, bfrag[1][4 + c], acc[1], 0, 0, 0);
        }
    }

    // ---- epilogue ----
#pragma unroll
    for (int s = 0; s < 2; ++s) {
        int feat = (2 * wave + s) * 16 + li;
        float bv = bias[feat];
#pragma unroll
        for (int r = 0; r < 4; ++r) {
            int node = m0 + sub * 4 + r;
            if (node < Nn) {
                float v = fmaxf(acc[s][r] + bv, 0.f);
                if (LAST) outf[(size_t)pos[node] * NF + feat] = v;
                else      outh[(size_t)node * NF + feat] = (_Float16)v;
            }
        }
    }
}

extern "C" void kernel_launch(void* const* d_in, const int* in_sizes, int n_in,
                              void* d_out, int out_size, void* d_ws, size_t ws_size,
                              hipStream_t stream) {
    const float* x   = (const float*)d_in[0];
    const int*   ei  = (const int*)d_in[1];   // [2,E] int32
    const int*   pos = (const int*)d_in[2];   // [N] int32 (== arange(N))
    const float* Wl1 = (const float*)d_in[4];
    const float* Wr1 = (const float*)d_in[5];
    const float* b1  = (const float*)d_in[6];
    const float* Wl2 = (const float*)d_in[7];
    const float* Wr2 = (const float*)d_in[8];
    const float* b2  = (const float*)d_in[9];
    float* out = (float*)d_out;

    const int Nn = in_sizes[0] / NF;      // 50000
    const int E  = in_sizes[1] / 2;       // 600000
    const int* src = ei;
    const int* dst = ei + E;
    const int pad_rows = out_size / NF;   // 60000

    // workspace: xh | h1h (Nn*NF f16) | Wf1 | Wf2 (32768 f16) |
    //            deg[degN] | csr[Nn*CAP] u32      (~39 MB)
    const int degN = (Nn + 3) & ~3;
    _Float16* xh   = (_Float16*)d_ws;
    _Float16* h1h  = xh + (size_t)Nn * NF;
    _Float16* Wf1  = h1h + (size_t)Nn * NF;
    _Float16* Wf2  = Wf1 + 64 * 64 * 8;
    int* deg       = (int*)(Wf2 + 64 * 64 * 8);
    int* csr       = deg + degN;

    const int ZB = 256;

    // 1) zero deg (graph-capture-safe async memset)
    hipMemsetAsync(deg, 0, (size_t)degN * sizeof(int), stream);

    // 2) mega: fill (first, long pole) | cvt | out-tail zero | swizzle
    int n4x = Nn * NF / 4;
    int n4tail = (pad_rows - Nn) * NF / 4;
    int nbe = (E + ZB - 1) / ZB;
    int nbc = (n4x + ZB - 1) / ZB;
    int nbt = (n4tail + ZB - 1) / ZB;
    mega_prep_kernel<<<nbe + nbc + nbt + 32, ZB, 0, stream>>>(
        src, dst, deg, csr, E,
        (const float4*)x, (f16x4*)xh, n4x,
        (float4*)(out + (size_t)Nn * NF), n4tail,
        Wl1, Wr1, Wf1, Wl2, Wr2, Wf2);

    // 3-4) fused layers (16 nodes per block)
    const int fblocks = (Nn + 15) / 16;   // 3125
    sage_layer_fused<false><<<fblocks, ZB, 0, stream>>>(
        csr, deg, xh, Wf1, b1, nullptr, h1h, nullptr, Nn);
    sage_layer_fused<true><<<fblocks, ZB, 0, stream>>>(
        csr, deg, h1h, Wf2, b2, pos, nullptr, out, Nn);
}